// Round 3
// 455.522 us; speedup vs baseline: 1.0075x; 1.0075x over previous
//
#include <hip/hip_runtime.h>
#include <math.h>

// AudioPreprocessingLayer: hamming * x -> rfft(512, norm=forward).real^2
//   -> mel(20x257) -> where(==0, 2^-52) -> floor(log2)
//
// Hybrid scheme (R2 resubmission; source tweaked to bypass any stale build
// cache after two broker-side container failures):
//   prep:   twiddle tables (f64+f32), padded filter bank, worklist count=0
//   phase1: fp32, TWO frames per wave (float4-interleaved LDS: element e =
//           (f0.re,f0.im,f1.re,f1.im)), 4 waves/block = 8 frames/block.
//           SINGLE in-place LDS buffer per wave (Stockham stage is in-place
//           safe: every output depends on all 4 inputs, so no ds_write can
//           precede the 4 ds_reads; DS pipe is in-order per wave; buffer is
//           wave-private). 20480 B/block -> 7-8 blocks/CU (was 38912 -> 4).
//           Stage 0 runs from registers (no initial LDS round-trip).
//           Stage 6 has j=0 -> twiddles are exactly (1,0): twiddle-free.
//           Untangle uses rex(256-k) = S_re - rex(k): one (zk,zc,wk) read
//           set yields BOTH spectrum halves; read-all-then-write makes the
//           pwr overlay of the FFT buffer hazard-free.
//           +1-per-8 float4 padding makes every stage conflict-free.
//           Frames with any log2(mel) within 1e-3 of an integer (or
//           mel<1e-30) are appended to a compacted worklist.
//   phase2: 4096 blocks grid-stride the worklist; each flagged frame (~4%)
//           recomputed with the R2-validated f64 pipeline.

#define MARGIN_L2 1.0e-3f
#define IDX(e) ((e) + ((e) >> 3))   // float4 units: pad 1 per 8 elements

__device__ __forceinline__ float4 f4add(float4 a, float4 b) {
    return make_float4(a.x + b.x, a.y + b.y, a.z + b.z, a.w + b.w);
}
__device__ __forceinline__ float4 f4sub(float4 a, float4 b) {
    return make_float4(a.x - b.x, a.y - b.y, a.z - b.z, a.w - b.w);
}
// w=(cos,sin) meaning e^{-i*theta}; applied to both packed complex values
__device__ __forceinline__ float4 cmulc4(float2 w, float4 z) {
    return make_float4(w.x * z.x + w.y * z.y, w.x * z.y - w.y * z.x,
                       w.x * z.z + w.y * z.w, w.x * z.w - w.y * z.z);
}

// Fused radix-2^2 butterfly (validated R3 formulas), packed 2 frames.
// In-place safe: all 4 reads are done by the caller before this writes,
// and each output depends on all 4 inputs (no write can be hoisted).
__device__ __forceinline__ void bfly4(int s, int l, const float2* tw,
                                      float4 x1, float4 y1, float4 x2, float4 y2,
                                      float4* dst) {
    const int j = l >> s;
    const int r = l & ((1 << s) - 1);
    const float2 w1 = tw[j << (s + 1)];
    const float2 w2 = tw[j << (s + 2)];
    const float4 u1 = f4add(x1, y1);
    const float4 v1 = cmulc4(w1, f4sub(x1, y1));
    const float4 u2 = f4add(x2, y2);
    const float4 m  = cmulc4(w1, f4sub(x2, y2));
    const float4 v2 = make_float4(m.y, -m.x, m.w, -m.z);   // -i * m
    const float4 o0 = f4add(u1, u2);
    const float4 o1 = cmulc4(w2, f4sub(u1, u2));
    const float4 o2 = f4add(v1, v2);
    const float4 o3 = cmulc4(w2, f4sub(v1, v2));
    const int eb = (j << (s + 2)) + r;
    dst[IDX(eb)]            = o0;
    dst[IDX(eb + (1 << s))] = o2;
    dst[IDX(eb + (2 << s))] = o1;
    dst[IDX(eb + (3 << s))] = o3;
}

// ---------------------------------------------------------------- prep ----
__global__ void prep_full(const float* __restrict__ fb,
                          double* __restrict__ tw64,
                          float2* __restrict__ tw32,
                          float* __restrict__ fbP,
                          unsigned* count) {
    const int t = threadIdx.x;  // 256
    double s, c;
    sincospi((double)t * (1.0 / 256.0), &s, &c);
    tw64[t]       = c;
    tw64[256 + t] = s;
    tw32[t] = make_float2((float)c, (float)s);
    for (int i = t; i < 20 * 264; i += 256) {
        const int m = i / 264, k = i % 264;
        fbP[i] = (k < 257) ? fb[m * 257 + k] : 0.0f;  // rows padded to 264
    }
    if (count && t == 0) *count = 0;
}

__global__ void prep_tw64(double* __restrict__ tw64) {
    const int t = threadIdx.x;
    double s, c;
    sincospi((double)t * (1.0 / 256.0), &s, &c);
    tw64[t]       = c;
    tw64[256 + t] = s;
}

// -------------------------------------------------------------- phase 1 ----
// fp32: 2 frames per wave, 4 waves per 256-thread block (8 frames/block).
// LDS = 4*288*16 + 2048 = 20480 B -> 7-8 blocks/CU.
__global__ __launch_bounds__(256, 7) void phase1(
    const float* __restrict__ x,      // (frames, 512)
    const float* __restrict__ hw,     // (512,)
    const float2* __restrict__ tw32,  // (256,) (cos,sin) of pi*k/256 (ws)
    const float* __restrict__ fbP,    // (20, 264) padded filter bank (ws)
    float* __restrict__ out,          // (frames, 20)
    unsigned* __restrict__ count,     // worklist count
    unsigned* __restrict__ worklist)  // flagged frame ids
{
    __shared__ __align__(16) float4 buf[4][288];   // 288 = IDX(255)+2 pad
    __shared__ __align__(16) float2 tw[256];

    const int t = threadIdx.x;
    const int w = t >> 6;     // wave id = frame-pair slot
    const int l = t & 63;     // lane
    const int fg0 = (blockIdx.x * 4 + w) * 2;
    const int fg1 = fg0 + 1;

    tw[t] = tw32[t];
    __syncthreads();   // tw ready (buf is wave-private)

    float4* const W = &buf[w][0];

    // Load + window + stage s=0 directly from registers -> W.
    // Element e holds (f0.re, f0.im, f1.re, f1.im); x1=e[l], x2=e[l+64],
    // y1=e[l+128], y2=e[l+192] -- exactly what stage 0 consumes.
    {
        const float2* xa = (const float2*)(x + (size_t)fg0 * 512);
        const float2* xb = (const float2*)(x + (size_t)fg1 * 512);
        const float2* hp = (const float2*)hw;
        const float2 h0 = hp[l],       h1 = hp[l + 64];
        const float2 h2 = hp[l + 128], h3 = hp[l + 192];
        const float2 a0 = xa[l],       a1 = xa[l + 64];
        const float2 a2 = xa[l + 128], a3 = xa[l + 192];
        const float2 b0 = xb[l],       b1 = xb[l + 64];
        const float2 b2 = xb[l + 128], b3 = xb[l + 192];
        const float4 x1 = make_float4(a0.x * h0.x, a0.y * h0.y,
                                      b0.x * h0.x, b0.y * h0.y);
        const float4 x2 = make_float4(a1.x * h1.x, a1.y * h1.y,
                                      b1.x * h1.x, b1.y * h1.y);
        const float4 y1 = make_float4(a2.x * h2.x, a2.y * h2.y,
                                      b2.x * h2.x, b2.y * h2.y);
        const float4 y2 = make_float4(a3.x * h3.x, a3.y * h3.y,
                                      b3.x * h3.x, b3.y * h3.y);
        bfly4(0, l, tw, x1, y1, x2, y2, W);
    }
    __builtin_amdgcn_wave_barrier();   // in-wave DS order; pin compiler

    // Stages s = 2, 4: in place (reads complete before writes within a
    // wave; every output depends on all 4 inputs).
#pragma unroll
    for (int s = 2; s <= 4; s += 2) {
        const float4 x1 = W[IDX(l)];
        const float4 y1 = W[IDX(l + 128)];
        const float4 x2 = W[IDX(l + 64)];
        const float4 y2 = W[IDX(l + 192)];
        bfly4(s, l, tw, x1, y1, x2, y2, W);
        __builtin_amdgcn_wave_barrier();
    }
    // Stage s = 6: j = l>>6 = 0 for every lane -> w1 = w2 = tw[0] = (1,0);
    // cmulc4((1,0),z) == z exactly, so skip the twiddle loads/muls.
    {
        const float4 x1 = W[IDX(l)];
        const float4 y1 = W[IDX(l + 128)];
        const float4 x2 = W[IDX(l + 64)];
        const float4 y2 = W[IDX(l + 192)];
        const float4 u1 = f4add(x1, y1);
        const float4 v1 = f4sub(x1, y1);
        const float4 u2 = f4add(x2, y2);
        const float4 m  = f4sub(x2, y2);
        const float4 v2 = make_float4(m.y, -m.x, m.w, -m.z);   // -i * m
        W[IDX(l)]       = f4add(u1, u2);
        W[IDX(l + 64)]  = f4add(v1, v2);
        W[IDX(l + 128)] = f4sub(u1, u2);
        W[IDX(l + 192)] = f4sub(v1, v2);
    }
    __builtin_amdgcn_wave_barrier();
    // Result (natural order) in W.

    // Untangle -> Re(rfft)_k, /512, square; symmetric-pair trick:
    //   rex(k)     = E + T,  E = 0.5*(zk.re+zc.re),
    //   rex(256-k) = E - T,  T = 0.5*(wk.x*(zk.im+zc.im) - wk.y*(zk.re-zc.re))
    // Lane l handles k = l (partner 256-l, l=0 -> Nyquist 256) and
    // k = l+64 (partner 192-l); lane 0 adds the self-paired k=128.
    // pwr overlays W: ALL reads are hoisted above the writes (wave_barrier
    // pins the compiler; wave lockstep + in-order DS pipe do the rest).
    float2* const pwr2 = (float2*)W;        // 264 float2, unpadded
    {
        const float4 zk0 = W[IDX(l)];
        const float4 zc0 = W[IDX((256 - l) & 255)];
        const float4 zk1 = W[IDX(l + 64)];
        const float4 zc1 = W[IDX(192 - l)];
        const float4 zm  = W[IDX(128)];          // broadcast; lane 0 uses
        const float2 w0 = tw[l];
        const float2 w1 = tw[l + 64];
        __builtin_amdgcn_wave_barrier();         // reads done; now write

        {
            const float SrA = zk0.x + zc0.x, SiA = zk0.y + zc0.y;
            const float DrA = zk0.x - zc0.x;
            const float SrB = zk0.z + zc0.z, SiB = zk0.w + zc0.w;
            const float DrB = zk0.z - zc0.z;
            const float EA = 0.5f * SrA, TA = 0.5f * (w0.x * SiA - w0.y * DrA);
            const float EB = 0.5f * SrB, TB = 0.5f * (w0.x * SiB - w0.y * DrB);
            const float aA = (EA + TA) * (1.0f / 512.0f);
            const float aB = (EB + TB) * (1.0f / 512.0f);
            const float bA = (EA - TA) * (1.0f / 512.0f);
            const float bB = (EB - TB) * (1.0f / 512.0f);
            pwr2[l]       = make_float2(aA * aA, aB * aB);
            pwr2[256 - l] = make_float2(bA * bA, bB * bB);  // l=0: Nyquist
        }
        {
            const float SrA = zk1.x + zc1.x, SiA = zk1.y + zc1.y;
            const float DrA = zk1.x - zc1.x;
            const float SrB = zk1.z + zc1.z, SiB = zk1.w + zc1.w;
            const float DrB = zk1.z - zc1.z;
            const float EA = 0.5f * SrA, TA = 0.5f * (w1.x * SiA - w1.y * DrA);
            const float EB = 0.5f * SrB, TB = 0.5f * (w1.x * SiB - w1.y * DrB);
            const float aA = (EA + TA) * (1.0f / 512.0f);
            const float aB = (EB + TB) * (1.0f / 512.0f);
            const float bA = (EA - TA) * (1.0f / 512.0f);
            const float bB = (EB - TB) * (1.0f / 512.0f);
            pwr2[l + 64]  = make_float2(aA * aA, aB * aB);
            pwr2[192 - l] = make_float2(bA * bA, bB * bB);
        }
        if (l == 0) {   // k = 128: wk = (0,1) -> rex = zk.re exactly
            const float vA = zm.x * (1.0f / 512.0f);
            const float vB = zm.z * (1.0f / 512.0f);
            pwr2[128] = make_float2(vA * vA, vB * vB);
        }
        if (l >= 57) pwr2[257 + (l - 57)] = make_float2(0.0f, 0.0f);
    }
    __builtin_amdgcn_wave_barrier();

    // Mel: lanes l<60: mel = l%20, sub = l/20 (88 bins each); one fb float4
    // (4 bins) serves BOTH frames; pwr pair j = bins 2j,2j+1 both frames.
    float accA = 0.0f, accB = 0.0f;
    if (l < 60) {
        const int mel = l % 20;
        const int sub = l / 20;
        const float4* fb4 = (const float4*)(fbP + mel * 264) + sub * 22;
        const float4* pw4 = (const float4*)pwr2 + sub * 44;
#pragma unroll
        for (int it = 0; it < 22; it++) {
            const float4 w4 = fb4[it];
            const float4 q0 = pw4[2 * it];       // (f0[4T],f1[4T],f0[4T+1],f1[4T+1])
            const float4 q1 = pw4[2 * it + 1];   // bins 4T+2, 4T+3
            accA = fmaf(w4.w, q1.z, fmaf(w4.z, q1.x,
                   fmaf(w4.y, q0.z, fmaf(w4.x, q0.x, accA))));
            accB = fmaf(w4.w, q1.w, fmaf(w4.z, q1.y,
                   fmaf(w4.y, q0.w, fmaf(w4.x, q0.y, accB))));
        }
    }
    const float pA1 = __shfl(accA, l + 20);
    const float pA2 = __shfl(accA, l + 40);
    const float pB1 = __shfl(accB, l + 20);
    const float pB2 = __shfl(accB, l + 40);

    int flagA = 0, flagB = 0;
    if (l < 20) {
        const float vA = accA + pA1 + pA2;
        float flA;
        if (vA < 1e-30f) { flA = -52.0f; flagA = 1; }
        else {
            const float l2 = log2f(vA);
            flA = floorf(l2);
            flagA = (l2 - flA < MARGIN_L2) | ((flA + 1.0f - l2) < MARGIN_L2);
        }
        out[(size_t)fg0 * 20 + l] = flA;

        const float vB = accB + pB1 + pB2;
        float flB;
        if (vB < 1e-30f) { flB = -52.0f; flagB = 1; }
        else {
            const float l2 = log2f(vB);
            flB = floorf(l2);
            flagB = (l2 - flB < MARGIN_L2) | ((flB + 1.0f - l2) < MARGIN_L2);
        }
        out[(size_t)fg1 * 20 + l] = flB;
    }
    const unsigned long long bA = __ballot(flagA);
    const unsigned long long bB = __ballot(flagB);
    if (l == 0) {
        const unsigned nf = (bA != 0ULL) + (bB != 0ULL);
        if (nf) {
            unsigned idx = atomicAdd(count, nf);
            if (bA != 0ULL) worklist[idx++] = (unsigned)fg0;
            if (bB != 0ULL) worklist[idx]   = (unsigned)fg1;
        }
    }
}

// ------------------------------------------- phase 2 (worklist repair) ----
__global__ __launch_bounds__(256) void phase2_wl(
    const float* __restrict__ x,
    const float* __restrict__ fb,
    const float* __restrict__ hw,
    const double* __restrict__ tw64,
    const unsigned* __restrict__ count,
    const unsigned* __restrict__ worklist,
    float* __restrict__ out)
{
    __shared__ double Are[256], Aim[256], Bre[256], Bim[256];
    __shared__ double ltc[256], lts[256];
    __shared__ double pwr[257];

    const int t = threadIdx.x;
    ltc[t] = tw64[t];
    lts[t] = tw64[256 + t];
    __syncthreads();

    const unsigned n = *count;
    for (unsigned i = blockIdx.x; i < n; i += gridDim.x) {
        const int f = (int)worklist[i];

        {
            const float2 xv = ((const float2*)x)[(size_t)f * 256 + t];
            const float2 hv = ((const float2*)hw)[t];
            Are[t] = (double)xv.x * (double)hv.x;
            Aim[t] = (double)xv.y * (double)hv.y;
        }
        __syncthreads();

        double* sre = Are; double* sim = Aim;
        double* dre = Bre; double* dim = Bim;
        const int p = t & 127;
        const int which = t >> 7;
#pragma unroll
        for (int s = 0; s < 8; s++) {
            const int j = p >> s;
            const double ar = sre[p],       ai = sim[p];
            const double br = sre[p + 128], bi = sim[p + 128];
            double orr, oi;
            int dpos;
            if (which) {
                const int idx = j << (s + 1);
                const double wr = ltc[idx];
                const double wi = -lts[idx];
                const double ur = ar - br, ui = ai - bi;
                orr = wr * ur - wi * ui;
                oi  = wr * ui + wi * ur;
                dpos = p + ((j + 1) << s);
            } else {
                orr = ar + br;
                oi  = ai + bi;
                dpos = p + (j << s);
            }
            dre[dpos] = orr;
            dim[dpos] = oi;
            __syncthreads();
            double* tmp;
            tmp = sre; sre = dre; dre = tmp;
            tmp = sim; sim = dim; dim = tmp;
        }

        {
            const double a = sre[t], b = sim[t];
            const int t2 = (256 - t) & 255;
            const double c = sre[t2], d = sim[t2];
            const double rex = 0.5 * (a + c)
                             + 0.5 * (ltc[t] * (b + d) - lts[t] * (a - c));
            const double v = rex * (1.0 / 512.0);
            pwr[t] = v * v;
            if (t == 0) {
                const double vn = (a - b) * (1.0 / 512.0);
                pwr[256] = vn * vn;
            }
        }
        __syncthreads();

        if (t < 160) {
            const int mel = t >> 3;
            const int sub = t & 7;
            const float* wrow = fb + mel * 257;
            double acc = 0.0;
            for (int k = sub; k < 257; k += 8)
                acc = fma((double)wrow[k], pwr[k], acc);
            acc += __shfl_down(acc, 4, 8);
            acc += __shfl_down(acc, 2, 8);
            acc += __shfl_down(acc, 1, 8);
            if (sub == 0) {
                double v = acc;
                if (v == 0.0) v = 2.220446049250313e-16;
                out[(size_t)f * 20 + mel] = (float)floor(log2(v));
            }
        }
        __syncthreads();
    }
}

// ------------------------------------------------- fallback: all-f64 (R2) ----
__global__ __launch_bounds__(256) void f64_all(
    const float*  __restrict__ x,
    const float*  __restrict__ fb,
    const float*  __restrict__ hw,
    const double* __restrict__ tw,
    float* __restrict__ out)
{
    __shared__ double Are[256], Aim[256], Bre[256], Bim[256];
    __shared__ double ltc[256], lts[256];
    __shared__ double pwr[257];

    const int t = threadIdx.x;
    const int f = blockIdx.x;

    ltc[t] = tw[t];
    lts[t] = tw[256 + t];
    {
        const float2 xv = ((const float2*)x)[(size_t)f * 256 + t];
        const float2 hv = ((const float2*)hw)[t];
        Are[t] = (double)xv.x * (double)hv.x;
        Aim[t] = (double)xv.y * (double)hv.y;
    }
    __syncthreads();

    double* sre = Are; double* sim = Aim;
    double* dre = Bre; double* dim = Bim;
    const int p = t & 127;
    const int which = t >> 7;
#pragma unroll
    for (int s = 0; s < 8; s++) {
        const int j = p >> s;
        const double ar = sre[p],       ai = sim[p];
        const double br = sre[p + 128], bi = sim[p + 128];
        double orr, oi;
        int dpos;
        if (which) {
            const int idx = j << (s + 1);
            const double wr = ltc[idx];
            const double wi = -lts[idx];
            const double ur = ar - br, ui = ai - bi;
            orr = wr * ur - wi * ui;
            oi  = wr * ui + wi * ur;
            dpos = p + ((j + 1) << s);
        } else {
            orr = ar + br;
            oi  = ai + bi;
            dpos = p + (j << s);
        }
        dre[dpos] = orr;
        dim[dpos] = oi;
        __syncthreads();
        double* tmp;
        tmp = sre; sre = dre; dre = tmp;
        tmp = sim; sim = dim; dim = tmp;
    }

    {
        const double a = sre[t], b = sim[t];
        const int t2 = (256 - t) & 255;
        const double c = sre[t2], d = sim[t2];
        const double rex = 0.5 * (a + c)
                         + 0.5 * (ltc[t] * (b + d) - lts[t] * (a - c));
        const double v = rex * (1.0 / 512.0);
        pwr[t] = v * v;
        if (t == 0) {
            const double vn = (a - b) * (1.0 / 512.0);
            pwr[256] = vn * vn;
        }
    }
    __syncthreads();

    if (t < 160) {
        const int mel = t >> 3;
        const int sub = t & 7;
        const float* wrow = fb + mel * 257;
        double acc = 0.0;
        for (int k = sub; k < 257; k += 8)
            acc = fma((double)wrow[k], pwr[k], acc);
        acc += __shfl_down(acc, 4, 8);
        acc += __shfl_down(acc, 2, 8);
        acc += __shfl_down(acc, 1, 8);
        if (sub == 0) {
            double v = acc;
            if (v == 0.0) v = 2.220446049250313e-16;
            out[(size_t)f * 20 + mel] = (float)floor(log2(v));
        }
    }
}

// ---------------------------------------------------------------- launch ----
extern "C" void kernel_launch(void* const* d_in, const int* in_sizes, int n_in,
                              void* d_out, int out_size, void* d_ws, size_t ws_size,
                              hipStream_t stream) {
    const float* x  = (const float*)d_in[0];   // (4096, 32, 512) f32
    const float* fb = (const float*)d_in[1];   // (20, 257) f32
    const float* hw = (const float*)d_in[2];   // (512,) f32
    float* out = (float*)d_out;

    const int frames = in_sizes[0] / 512;      // 131072

    char* ws = (char*)d_ws;
    double* tw64 = (double*)ws;                          // 4096 B
    float2* tw32 = (float2*)(ws + 4096);                 // 2048 B
    float*  fbP  = (float*)(ws + 6144);                  // 21120 B

    const size_t T1 = 32832 + 4 * (size_t)frames;        // count + worklist

    if (ws_size >= T1 && (frames % 8) == 0) {
        unsigned* count    = (unsigned*)(ws + 32768);
        unsigned* worklist = (unsigned*)(ws + 32832);
        prep_full<<<1, 256, 0, stream>>>(fb, tw64, tw32, fbP, count);
        phase1<<<frames / 8, 256, 0, stream>>>(x, hw, tw32, fbP, out,
                                               count, worklist);
        phase2_wl<<<4096, 256, 0, stream>>>(x, fb, hw, tw64, count, worklist, out);
    } else {
        prep_tw64<<<1, 256, 0, stream>>>(tw64);
        f64_all<<<frames, 256, 0, stream>>>(x, fb, hw, tw64, out);
    }
}

// Round 4
// 420.731 us; speedup vs baseline: 1.0908x; 1.0827x over previous
//
#include <hip/hip_runtime.h>
#include <math.h>

// AudioPreprocessingLayer: hamming * x -> rfft(512, norm=forward).real^2
//   -> mel(20x257) -> where(==0, 2^-52) -> floor(log2)
//
// Hybrid scheme:
//   prep:   twiddle tables (f64+f32), COMPACTED filter bank (per-mel support
//           [g0, g0+ng) in 4-bin groups; max ng = 18 for this bank), packed
//           meta = g0 | ng<<16, worklist count=0.
//   phase1: fp32, TWO frames per wave (float4-interleaved LDS: element e =
//           (f0.re,f0.im,f1.re,f1.im)), 4 waves/block = 8 frames/block.
//           SINGLE in-place LDS buffer per wave (Stockham stage is in-place
//           safe: every output depends on all 4 inputs, so no ds_write can
//           precede the 4 ds_reads; DS pipe is in-order per wave; buffer is
//           wave-private). 20480 B/block, launch_bounds(256,8) -> 8 blocks/CU.
//           Stage 0 runs from registers; stage 6 is twiddle-free (j=0).
//           Untangle uses rex(256-k) = S_re - rex(k): one (zk,zc,wk) read
//           set yields BOTH spectrum halves, read-all-then-write.
//           MEL USES COMPACT SUPPORT: the R3 profile showed the mel loop's
//           44 ds_read_b128/wave dominated the DS pipe (more than the whole
//           FFT at 33); iterating only the triangular support cuts that to
//           <=12 reads/wave (ceil(ng/3) <= 6 iters x q0,q1).
//           Frames with any log2(mel) within 1e-3 of an integer (or
//           mel<1e-30) are appended to a compacted worklist.
//   phase2: 4096 blocks grid-stride the worklist; each flagged frame (~4%)
//           recomputed with the R2-validated f64 pipeline (margin 1e-3 >>
//           fp32 summation-order ulps, so the fp32 order change is safe).

#define MARGIN_L2 1.0e-3f
#define IDX(e) ((e) + ((e) >> 3))   // float4 units: pad 1 per 8 elements
#define WCSTRIDE 20                 // float4 groups per mel row (>= max ng 18)

__device__ __forceinline__ float4 f4add(float4 a, float4 b) {
    return make_float4(a.x + b.x, a.y + b.y, a.z + b.z, a.w + b.w);
}
__device__ __forceinline__ float4 f4sub(float4 a, float4 b) {
    return make_float4(a.x - b.x, a.y - b.y, a.z - b.z, a.w - b.w);
}
// w=(cos,sin) meaning e^{-i*theta}; applied to both packed complex values
__device__ __forceinline__ float4 cmulc4(float2 w, float4 z) {
    return make_float4(w.x * z.x + w.y * z.y, w.x * z.y - w.y * z.x,
                       w.x * z.z + w.y * z.w, w.x * z.w - w.y * z.z);
}

// Fused radix-2^2 butterfly (validated R3 formulas), packed 2 frames.
// In-place safe: all 4 reads are done by the caller before this writes,
// and each output depends on all 4 inputs (no write can be hoisted).
__device__ __forceinline__ void bfly4(int s, int l, const float2* tw,
                                      float4 x1, float4 y1, float4 x2, float4 y2,
                                      float4* dst) {
    const int j = l >> s;
    const int r = l & ((1 << s) - 1);
    const float2 w1 = tw[j << (s + 1)];
    const float2 w2 = tw[j << (s + 2)];
    const float4 u1 = f4add(x1, y1);
    const float4 v1 = cmulc4(w1, f4sub(x1, y1));
    const float4 u2 = f4add(x2, y2);
    const float4 m  = cmulc4(w1, f4sub(x2, y2));
    const float4 v2 = make_float4(m.y, -m.x, m.w, -m.z);   // -i * m
    const float4 o0 = f4add(u1, u2);
    const float4 o1 = cmulc4(w2, f4sub(u1, u2));
    const float4 o2 = f4add(v1, v2);
    const float4 o3 = cmulc4(w2, f4sub(v1, v2));
    const int eb = (j << (s + 2)) + r;
    dst[IDX(eb)]            = o0;
    dst[IDX(eb + (1 << s))] = o2;
    dst[IDX(eb + (2 << s))] = o1;
    dst[IDX(eb + (3 << s))] = o3;
}

// ---------------------------------------------------------------- prep ----
__global__ void prep_full(const float* __restrict__ fb,
                          double* __restrict__ tw64,
                          float2* __restrict__ tw32,
                          float4* __restrict__ wc,    // (20, WCSTRIDE) compact
                          int*    __restrict__ meta,  // (20,) g0 | ng<<16
                          unsigned* count) {
    __shared__ int sg0[20], sng[20];
    const int t = threadIdx.x;  // 256
    double s, c;
    sincospi((double)t * (1.0 / 256.0), &s, &c);
    tw64[t]       = c;
    tw64[256 + t] = s;
    tw32[t] = make_float2((float)c, (float)s);

    if (t < 20) {   // nonzero-support scan for mel row t
        int lo = 257, hi = 0;
        for (int k = 0; k < 257; k++) {
            if (fb[t * 257 + k] > 0.0f) {
                if (k < lo) lo = k;
                hi = k + 1;
            }
        }
        if (hi <= lo) { lo = 0; hi = 1; }         // degenerate guard
        int g0 = lo >> 2;
        int ng = ((hi + 3) >> 2) - g0;
        if (ng > WCSTRIDE) ng = WCSTRIDE;         // never binds for this bank
        sg0[t] = g0; sng[t] = ng;
        meta[t] = g0 | (ng << 16);
    }
    __syncthreads();

    for (int i = t; i < 20 * WCSTRIDE; i += 256) {
        const int m = i / WCSTRIDE, j = i % WCSTRIDE;
        float4 v = make_float4(0.0f, 0.0f, 0.0f, 0.0f);
        if (j < sng[m]) {
            const int b = (sg0[m] + j) * 4;
            const float* row = fb + m * 257;
            v.x = (b + 0 < 257) ? row[b + 0] : 0.0f;
            v.y = (b + 1 < 257) ? row[b + 1] : 0.0f;
            v.z = (b + 2 < 257) ? row[b + 2] : 0.0f;
            v.w = (b + 3 < 257) ? row[b + 3] : 0.0f;
        }
        wc[i] = v;
    }
    if (count && t == 0) *count = 0;
}

__global__ void prep_tw64(double* __restrict__ tw64) {
    const int t = threadIdx.x;
    double s, c;
    sincospi((double)t * (1.0 / 256.0), &s, &c);
    tw64[t]       = c;
    tw64[256 + t] = s;
}

// -------------------------------------------------------------- phase 1 ----
// fp32: 2 frames per wave, 4 waves per 256-thread block (8 frames/block).
// LDS = 4*288*16 + 2048 = 20480 B; 8 blocks/CU = exactly 160 KiB.
__global__ __launch_bounds__(256, 8) void phase1(
    const float* __restrict__ x,      // (frames, 512)
    const float* __restrict__ hw,     // (512,)
    const float2* __restrict__ tw32,  // (256,) (cos,sin) of pi*k/256 (ws)
    const float4* __restrict__ wc,    // (20, WCSTRIDE) compact filter bank
    const int*    __restrict__ meta,  // (20,) g0 | ng<<16
    float* __restrict__ out,          // (frames, 20)
    unsigned* __restrict__ count,     // worklist count
    unsigned* __restrict__ worklist)  // flagged frame ids
{
    __shared__ __align__(16) float4 buf[4][288];   // 288 = IDX(255)+2 pad
    __shared__ __align__(16) float2 tw[256];

    const int t = threadIdx.x;
    const int w = t >> 6;     // wave id = frame-pair slot
    const int l = t & 63;     // lane
    const int fg0 = (blockIdx.x * 4 + w) * 2;
    const int fg1 = fg0 + 1;

    tw[t] = tw32[t];
    __syncthreads();   // tw ready (buf is wave-private)

    float4* const W = &buf[w][0];

    // Load + window + stage s=0 directly from registers -> W.
    // Element e holds (f0.re, f0.im, f1.re, f1.im); x1=e[l], x2=e[l+64],
    // y1=e[l+128], y2=e[l+192] -- exactly what stage 0 consumes.
    {
        const float2* xa = (const float2*)(x + (size_t)fg0 * 512);
        const float2* xb = (const float2*)(x + (size_t)fg1 * 512);
        const float2* hp = (const float2*)hw;
        const float2 h0 = hp[l],       h1 = hp[l + 64];
        const float2 h2 = hp[l + 128], h3 = hp[l + 192];
        const float2 a0 = xa[l],       a1 = xa[l + 64];
        const float2 a2 = xa[l + 128], a3 = xa[l + 192];
        const float2 b0 = xb[l],       b1 = xb[l + 64];
        const float2 b2 = xb[l + 128], b3 = xb[l + 192];
        const float4 x1 = make_float4(a0.x * h0.x, a0.y * h0.y,
                                      b0.x * h0.x, b0.y * h0.y);
        const float4 x2 = make_float4(a1.x * h1.x, a1.y * h1.y,
                                      b1.x * h1.x, b1.y * h1.y);
        const float4 y1 = make_float4(a2.x * h2.x, a2.y * h2.y,
                                      b2.x * h2.x, b2.y * h2.y);
        const float4 y2 = make_float4(a3.x * h3.x, a3.y * h3.y,
                                      b3.x * h3.x, b3.y * h3.y);
        bfly4(0, l, tw, x1, y1, x2, y2, W);
    }
    __builtin_amdgcn_wave_barrier();   // in-wave DS order; pin compiler

    // Stages s = 2, 4: in place (reads complete before writes within a
    // wave; every output depends on all 4 inputs).
#pragma unroll
    for (int s = 2; s <= 4; s += 2) {
        const float4 x1 = W[IDX(l)];
        const float4 y1 = W[IDX(l + 128)];
        const float4 x2 = W[IDX(l + 64)];
        const float4 y2 = W[IDX(l + 192)];
        bfly4(s, l, tw, x1, y1, x2, y2, W);
        __builtin_amdgcn_wave_barrier();
    }
    // Stage s = 6: j = l>>6 = 0 for every lane -> w1 = w2 = tw[0] = (1,0);
    // cmulc4((1,0),z) == z exactly, so skip the twiddle loads/muls.
    {
        const float4 x1 = W[IDX(l)];
        const float4 y1 = W[IDX(l + 128)];
        const float4 x2 = W[IDX(l + 64)];
        const float4 y2 = W[IDX(l + 192)];
        const float4 u1 = f4add(x1, y1);
        const float4 v1 = f4sub(x1, y1);
        const float4 u2 = f4add(x2, y2);
        const float4 m  = f4sub(x2, y2);
        const float4 v2 = make_float4(m.y, -m.x, m.w, -m.z);   // -i * m
        W[IDX(l)]       = f4add(u1, u2);
        W[IDX(l + 64)]  = f4add(v1, v2);
        W[IDX(l + 128)] = f4sub(u1, u2);
        W[IDX(l + 192)] = f4sub(v1, v2);
    }
    __builtin_amdgcn_wave_barrier();
    // Result (natural order) in W.

    // Untangle -> Re(rfft)_k, /512, square; symmetric-pair trick:
    //   rex(k)     = E + T,  E = 0.5*(zk.re+zc.re),
    //   rex(256-k) = E - T,  T = 0.5*(wk.x*(zk.im+zc.im) - wk.y*(zk.re-zc.re))
    // Lane l handles k = l (partner 256-l, l=0 -> Nyquist 256) and
    // k = l+64 (partner 192-l); lane 0 adds the self-paired k=128.
    // pwr overlays W: ALL reads are hoisted above the writes (wave_barrier
    // pins the compiler; wave lockstep + in-order DS pipe do the rest).
    float2* const pwr2 = (float2*)W;        // 264 float2, unpadded
    {
        const float4 zk0 = W[IDX(l)];
        const float4 zc0 = W[IDX((256 - l) & 255)];
        const float4 zk1 = W[IDX(l + 64)];
        const float4 zc1 = W[IDX(192 - l)];
        const float4 zm  = W[IDX(128)];          // broadcast; lane 0 uses
        const float2 w0 = tw[l];
        const float2 w1 = tw[l + 64];
        __builtin_amdgcn_wave_barrier();         // reads done; now write

        {
            const float SrA = zk0.x + zc0.x, SiA = zk0.y + zc0.y;
            const float DrA = zk0.x - zc0.x;
            const float SrB = zk0.z + zc0.z, SiB = zk0.w + zc0.w;
            const float DrB = zk0.z - zc0.z;
            const float EA = 0.5f * SrA, TA = 0.5f * (w0.x * SiA - w0.y * DrA);
            const float EB = 0.5f * SrB, TB = 0.5f * (w0.x * SiB - w0.y * DrB);
            const float aA = (EA + TA) * (1.0f / 512.0f);
            const float aB = (EB + TB) * (1.0f / 512.0f);
            const float bA = (EA - TA) * (1.0f / 512.0f);
            const float bB = (EB - TB) * (1.0f / 512.0f);
            pwr2[l]       = make_float2(aA * aA, aB * aB);
            pwr2[256 - l] = make_float2(bA * bA, bB * bB);  // l=0: Nyquist
        }
        {
            const float SrA = zk1.x + zc1.x, SiA = zk1.y + zc1.y;
            const float DrA = zk1.x - zc1.x;
            const float SrB = zk1.z + zc1.z, SiB = zk1.w + zc1.w;
            const float DrB = zk1.z - zc1.z;
            const float EA = 0.5f * SrA, TA = 0.5f * (w1.x * SiA - w1.y * DrA);
            const float EB = 0.5f * SrB, TB = 0.5f * (w1.x * SiB - w1.y * DrB);
            const float aA = (EA + TA) * (1.0f / 512.0f);
            const float aB = (EB + TB) * (1.0f / 512.0f);
            const float bA = (EA - TA) * (1.0f / 512.0f);
            const float bB = (EB - TB) * (1.0f / 512.0f);
            pwr2[l + 64]  = make_float2(aA * aA, aB * aB);
            pwr2[192 - l] = make_float2(bA * bA, bB * bB);
        }
        if (l == 0) {   // k = 128: wk = (0,1) -> rex = zk.re exactly
            const float vA = zm.x * (1.0f / 512.0f);
            const float vB = zm.z * (1.0f / 512.0f);
            pwr2[128] = make_float2(vA * vA, vB * vB);
        }
        if (l >= 57) pwr2[257 + (l - 57)] = make_float2(0.0f, 0.0f);
    }
    __builtin_amdgcn_wave_barrier();

    // Mel over COMPACT support: lanes l<60: mel = l%20, sub = l/20; lane
    // iterates groups j = sub, sub+3, ... < ng (max 6 iters for ng<=18).
    // Group g covers bins 4g..4g+3: q0 = pw4[2g] (bins 4g,4g+1 both frames),
    // q1 = pw4[2g+1]. Out-of-support groups contribute exact 0 (wc padded).
    float accA = 0.0f, accB = 0.0f;
    if (l < 60) {
        const int mel = l % 20;
        const int sub = l / 20;
        const int mw  = meta[mel];
        const int g0m = mw & 0xffff;
        const int ngm = mw >> 16;
        const float4* wrow = wc + mel * WCSTRIDE;
        const float4* pw4  = (const float4*)pwr2 + 2 * g0m;
        for (int j = sub; j < ngm; j += 3) {
            const float4 w4 = wrow[j];
            const float4 q0 = pw4[2 * j];
            const float4 q1 = pw4[2 * j + 1];
            accA = fmaf(w4.w, q1.z, fmaf(w4.z, q1.x,
                   fmaf(w4.y, q0.z, fmaf(w4.x, q0.x, accA))));
            accB = fmaf(w4.w, q1.w, fmaf(w4.z, q1.y,
                   fmaf(w4.y, q0.w, fmaf(w4.x, q0.y, accB))));
        }
    }
    const float pA1 = __shfl(accA, l + 20);
    const float pA2 = __shfl(accA, l + 40);
    const float pB1 = __shfl(accB, l + 20);
    const float pB2 = __shfl(accB, l + 40);

    int flagA = 0, flagB = 0;
    if (l < 20) {
        const float vA = accA + pA1 + pA2;
        float flA;
        if (vA < 1e-30f) { flA = -52.0f; flagA = 1; }
        else {
            const float l2 = log2f(vA);
            flA = floorf(l2);
            flagA = (l2 - flA < MARGIN_L2) | ((flA + 1.0f - l2) < MARGIN_L2);
        }
        out[(size_t)fg0 * 20 + l] = flA;

        const float vB = accB + pB1 + pB2;
        float flB;
        if (vB < 1e-30f) { flB = -52.0f; flagB = 1; }
        else {
            const float l2 = log2f(vB);
            flB = floorf(l2);
            flagB = (l2 - flB < MARGIN_L2) | ((flB + 1.0f - l2) < MARGIN_L2);
        }
        out[(size_t)fg1 * 20 + l] = flB;
    }
    const unsigned long long bA = __ballot(flagA);
    const unsigned long long bB = __ballot(flagB);
    if (l == 0) {
        const unsigned nf = (bA != 0ULL) + (bB != 0ULL);
        if (nf) {
            unsigned idx = atomicAdd(count, nf);
            if (bA != 0ULL) worklist[idx++] = (unsigned)fg0;
            if (bB != 0ULL) worklist[idx]   = (unsigned)fg1;
        }
    }
}

// ------------------------------------------- phase 2 (worklist repair) ----
__global__ __launch_bounds__(256) void phase2_wl(
    const float* __restrict__ x,
    const float* __restrict__ fb,
    const float* __restrict__ hw,
    const double* __restrict__ tw64,
    const unsigned* __restrict__ count,
    const unsigned* __restrict__ worklist,
    float* __restrict__ out)
{
    __shared__ double Are[256], Aim[256], Bre[256], Bim[256];
    __shared__ double ltc[256], lts[256];
    __shared__ double pwr[257];

    const int t = threadIdx.x;
    ltc[t] = tw64[t];
    lts[t] = tw64[256 + t];
    __syncthreads();

    const unsigned n = *count;
    for (unsigned i = blockIdx.x; i < n; i += gridDim.x) {
        const int f = (int)worklist[i];

        {
            const float2 xv = ((const float2*)x)[(size_t)f * 256 + t];
            const float2 hv = ((const float2*)hw)[t];
            Are[t] = (double)xv.x * (double)hv.x;
            Aim[t] = (double)xv.y * (double)hv.y;
        }
        __syncthreads();

        double* sre = Are; double* sim = Aim;
        double* dre = Bre; double* dim = Bim;
        const int p = t & 127;
        const int which = t >> 7;
#pragma unroll
        for (int s = 0; s < 8; s++) {
            const int j = p >> s;
            const double ar = sre[p],       ai = sim[p];
            const double br = sre[p + 128], bi = sim[p + 128];
            double orr, oi;
            int dpos;
            if (which) {
                const int idx = j << (s + 1);
                const double wr = ltc[idx];
                const double wi = -lts[idx];
                const double ur = ar - br, ui = ai - bi;
                orr = wr * ur - wi * ui;
                oi  = wr * ui + wi * ur;
                dpos = p + ((j + 1) << s);
            } else {
                orr = ar + br;
                oi  = ai + bi;
                dpos = p + (j << s);
            }
            dre[dpos] = orr;
            dim[dpos] = oi;
            __syncthreads();
            double* tmp;
            tmp = sre; sre = dre; dre = tmp;
            tmp = sim; sim = dim; dim = tmp;
        }

        {
            const double a = sre[t], b = sim[t];
            const int t2 = (256 - t) & 255;
            const double c = sre[t2], d = sim[t2];
            const double rex = 0.5 * (a + c)
                             + 0.5 * (ltc[t] * (b + d) - lts[t] * (a - c));
            const double v = rex * (1.0 / 512.0);
            pwr[t] = v * v;
            if (t == 0) {
                const double vn = (a - b) * (1.0 / 512.0);
                pwr[256] = vn * vn;
            }
        }
        __syncthreads();

        if (t < 160) {
            const int mel = t >> 3;
            const int sub = t & 7;
            const float* wrow = fb + mel * 257;
            double acc = 0.0;
            for (int k = sub; k < 257; k += 8)
                acc = fma((double)wrow[k], pwr[k], acc);
            acc += __shfl_down(acc, 4, 8);
            acc += __shfl_down(acc, 2, 8);
            acc += __shfl_down(acc, 1, 8);
            if (sub == 0) {
                double v = acc;
                if (v == 0.0) v = 2.220446049250313e-16;
                out[(size_t)f * 20 + mel] = (float)floor(log2(v));
            }
        }
        __syncthreads();
    }
}

// ------------------------------------------------- fallback: all-f64 (R2) ----
__global__ __launch_bounds__(256) void f64_all(
    const float*  __restrict__ x,
    const float*  __restrict__ fb,
    const float*  __restrict__ hw,
    const double* __restrict__ tw,
    float* __restrict__ out)
{
    __shared__ double Are[256], Aim[256], Bre[256], Bim[256];
    __shared__ double ltc[256], lts[256];
    __shared__ double pwr[257];

    const int t = threadIdx.x;
    const int f = blockIdx.x;

    ltc[t] = tw[t];
    lts[t] = tw[256 + t];
    {
        const float2 xv = ((const float2*)x)[(size_t)f * 256 + t];
        const float2 hv = ((const float2*)hw)[t];
        Are[t] = (double)xv.x * (double)hv.x;
        Aim[t] = (double)xv.y * (double)hv.y;
    }
    __syncthreads();

    double* sre = Are; double* sim = Aim;
    double* dre = Bre; double* dim = Bim;
    const int p = t & 127;
    const int which = t >> 7;
#pragma unroll
    for (int s = 0; s < 8; s++) {
        const int j = p >> s;
        const double ar = sre[p],       ai = sim[p];
        const double br = sre[p + 128], bi = sim[p + 128];
        double orr, oi;
        int dpos;
        if (which) {
            const int idx = j << (s + 1);
            const double wr = ltc[idx];
            const double wi = -lts[idx];
            const double ur = ar - br, ui = ai - bi;
            orr = wr * ur - wi * ui;
            oi  = wr * ui + wi * ur;
            dpos = p + ((j + 1) << s);
        } else {
            orr = ar + br;
            oi  = ai + bi;
            dpos = p + (j << s);
        }
        dre[dpos] = orr;
        dim[dpos] = oi;
        __syncthreads();
        double* tmp;
        tmp = sre; sre = dre; dre = tmp;
        tmp = sim; sim = dim; dim = tmp;
    }

    {
        const double a = sre[t], b = sim[t];
        const int t2 = (256 - t) & 255;
        const double c = sre[t2], d = sim[t2];
        const double rex = 0.5 * (a + c)
                         + 0.5 * (ltc[t] * (b + d) - lts[t] * (a - c));
        const double v = rex * (1.0 / 512.0);
        pwr[t] = v * v;
        if (t == 0) {
            const double vn = (a - b) * (1.0 / 512.0);
            pwr[256] = vn * vn;
        }
    }
    __syncthreads();

    if (t < 160) {
        const int mel = t >> 3;
        const int sub = t & 7;
        const float* wrow = fb + mel * 257;
        double acc = 0.0;
        for (int k = sub; k < 257; k += 8)
            acc = fma((double)wrow[k], pwr[k], acc);
        acc += __shfl_down(acc, 4, 8);
        acc += __shfl_down(acc, 2, 8);
        acc += __shfl_down(acc, 1, 8);
        if (sub == 0) {
            double v = acc;
            if (v == 0.0) v = 2.220446049250313e-16;
            out[(size_t)f * 20 + mel] = (float)floor(log2(v));
        }
    }
}

// ---------------------------------------------------------------- launch ----
extern "C" void kernel_launch(void* const* d_in, const int* in_sizes, int n_in,
                              void* d_out, int out_size, void* d_ws, size_t ws_size,
                              hipStream_t stream) {
    const float* x  = (const float*)d_in[0];   // (4096, 32, 512) f32
    const float* fb = (const float*)d_in[1];   // (20, 257) f32
    const float* hw = (const float*)d_in[2];   // (512,) f32
    float* out = (float*)d_out;

    const int frames = in_sizes[0] / 512;      // 131072

    char* ws = (char*)d_ws;
    double* tw64 = (double*)ws;                          // 4096 B
    float2* tw32 = (float2*)(ws + 4096);                 // 2048 B
    float4* wc   = (float4*)(ws + 6144);                 // 20*20*16 = 6400 B
    int*    meta = (int*)(ws + 12544);                   // 80 B

    const size_t T1 = 32832 + 4 * (size_t)frames;        // count + worklist

    if (ws_size >= T1 && (frames % 8) == 0) {
        unsigned* count    = (unsigned*)(ws + 32768);
        unsigned* worklist = (unsigned*)(ws + 32832);
        prep_full<<<1, 256, 0, stream>>>(fb, tw64, tw32, wc, meta, count);
        phase1<<<frames / 8, 256, 0, stream>>>(x, hw, tw32, wc, meta, out,
                                               count, worklist);
        phase2_wl<<<4096, 256, 0, stream>>>(x, fb, hw, tw64, count, worklist, out);
    } else {
        prep_tw64<<<1, 256, 0, stream>>>(tw64);
        f64_all<<<frames, 256, 0, stream>>>(x, fb, hw, tw64, out);
    }
}